// Round 1
// baseline (229.020 us; speedup 1.0000x reference)
//
#include <hip/hip_runtime.h>

#define NT 16
#define NTILES 256
#define INV_TILE (1.0f/64.0f)

__device__ __forceinline__ int tile_of(float x, float y) {
    int tx = (int)floorf(x * INV_TILE);
    tx = tx < 0 ? 0 : (tx > NT - 1 ? NT - 1 : tx);
    int ty = (int)floorf(y * INV_TILE);
    ty = ty < 0 ? 0 : (ty > NT - 1 ? NT - 1 : ty);
    return ty * NT + tx;
}

// Compute the 64-lane same-tile group mask via 8 ballots (tile id is 8 bits).
__device__ __forceinline__ unsigned long long match_mask(int t, bool valid) {
    unsigned long long m = ~0ull;
#pragma unroll
    for (int b = 0; b < 8; ++b) {
        unsigned long long bal = __ballot((t >> b) & 1);
        m &= ((t >> b) & 1) ? bal : ~bal;
    }
    m &= __ballot(valid);
    return m;
}

// K1: per-wave 256-bin histogram of a contiguous 512-pt chunk + global totals.
__global__ __launch_bounds__(256) void k_hist(const float2* __restrict__ pos2d,
                                              int* __restrict__ gHist,
                                              int* __restrict__ gcounts,
                                              int N, int wchunk) {
    __shared__ int counters[4][NTILES];
    const int tid = threadIdx.x;
    const int wl = tid >> 6, lane = tid & 63;
#pragma unroll
    for (int k = 0; k < 4; ++k) counters[wl][lane + 64 * k] = 0;   // wave-private, no barrier
    const int w = blockIdx.x * 4 + wl;
    const int start = w * wchunk;
    const int rounds = wchunk >> 6;
    for (int r = 0; r < rounds; ++r) {
        int i = start + r * 64 + lane;
        bool valid = i < N;
        int t = 0;
        if (valid) { float2 p = pos2d[i]; t = tile_of(p.x, p.y); }
        unsigned long long m = match_mask(t, valid);
        if (valid) {
            unsigned long long below = m & ((1ull << lane) - 1ull);
            if (below == 0ull) counters[wl][t] += __popcll(m);     // one leader per tile-group
        }
    }
#pragma unroll
    for (int k = 0; k < 4; ++k)
        gHist[(size_t)w * NTILES + lane + 64 * k] = counters[wl][lane + 64 * k];
    __syncthreads();
    int s = counters[0][tid] + counters[1][tid] + counters[2][tid] + counters[3][tid];
    if (s) atomicAdd(&gcounts[tid], s);
}

// K2: one block per tile. Cross-tile exclusive offset + column scan of hist
// rows (converted in place into per-(wave,tile) output bases).
__global__ __launch_bounds__(256) void k_scan(const int* __restrict__ gcounts,
                                              int* __restrict__ gHist,
                                              float* __restrict__ out_counts,
                                              float* __restrict__ out_offsets,
                                              int NWA) {
    const int t = blockIdx.x;
    const int tid = threadIdx.x;
    const int wl = tid >> 6, lane = tid & 63;
    __shared__ int sdata[NTILES];
    __shared__ int wsum[4];

    int v = (tid < t) ? gcounts[tid] : 0;           // offset_t = sum_{u<t} counts[u]
    sdata[tid] = v;
    __syncthreads();
#pragma unroll
    for (int s = 128; s > 0; s >>= 1) {
        if (tid < s) sdata[tid] += sdata[tid + s];
        __syncthreads();
    }
    int offset_t = sdata[0];
    if (tid == 0) {
        out_counts[t]  = (float)gcounts[t];
        out_offsets[t] = (float)offset_t;
    }

    // Thread tid owns rows [tid*16, tid*16+16) of this tile's column (NWA<=4096).
    int vals[16];
    const int base_row = tid * 16;
#pragma unroll
    for (int k = 0; k < 16; ++k) {
        int row = base_row + k;
        vals[k] = (row < NWA) ? gHist[(size_t)row * NTILES + t] : 0;
    }
    int tv = 0;
#pragma unroll
    for (int k = 0; k < 16; ++k) tv += vals[k];
    int x = tv;                                     // wave inclusive scan
#pragma unroll
    for (int s = 1; s < 64; s <<= 1) {
        int y = __shfl_up(x, s);
        if (lane >= s) x += y;
    }
    if (lane == 63) wsum[wl] = x;
    __syncthreads();
    int wprefix = 0;
    for (int u = 0; u < wl; ++u) wprefix += wsum[u];
    int running = offset_t + wprefix + (x - tv);    // block-exclusive + tile offset
#pragma unroll
    for (int k = 0; k < 16; ++k) {
        int row = base_row + k;
        if (row < NWA) gHist[(size_t)row * NTILES + t] = running;
        running += vals[k];
    }
}

// K3: recompute tile + features, rank via ballots, scatter to sorted output.
__global__ __launch_bounds__(256) void k_scatter(const float2* __restrict__ pos2d,
                                                 const float4* __restrict__ cov2d,
                                                 const float*  __restrict__ opacity,
                                                 const int*    __restrict__ gBase,
                                                 float* __restrict__ out_feat,
                                                 float* __restrict__ out_order,
                                                 int N, int wchunk) {
    __shared__ int counters[4][NTILES];
    const int tid = threadIdx.x;
    const int wl = tid >> 6, lane = tid & 63;
    const int w = blockIdx.x * 4 + wl;
#pragma unroll
    for (int k = 0; k < 4; ++k)
        counters[wl][lane + 64 * k] = gBase[(size_t)w * NTILES + lane + 64 * k];
    const int start = w * wchunk;
    const int rounds = wchunk >> 6;
    for (int r = 0; r < rounds; ++r) {
        int i = start + r * 64 + lane;
        bool valid = i < N;
        int t = 0;
        float px = 0, py = 0, c0 = 0, c1 = 0, c2 = 0, op = 0, rad = 0;
        if (valid) {
            float2 p = pos2d[i];
            px = p.x; py = p.y;
            t = tile_of(px, py);
            float4 cv = cov2d[i];
            float a = cv.x, b = cv.y, c = cv.z, d = cv.w;
            float trace = a + d;
            float det = a * d - b * c;
            float term1 = 0.5f * trace;
            float term2 = 0.5f * sqrtf(fmaxf(trace * trace - 4.0f * det, 0.0f));
            rad = fmaxf(term1 - term2, term1 + term2);
            float inv = 1.0f / det;
            c0 = d * inv; c1 = -b * inv; c2 = a * inv;
            op = opacity[i];
        }
        unsigned long long m = match_mask(t, valid);
        if (valid) {
            unsigned long long below = m & ((1ull << lane) - 1ull);
            int rank = __popcll(below);
            int base = counters[wl][t];                       // lockstep: read precedes
            if (below == 0ull) counters[wl][t] = base + __popcll(m);  // leader write
            size_t p = (size_t)(base + rank);
            float* fr = out_feat + p * 7;
            fr[0] = px; fr[1] = py; fr[2] = c0; fr[3] = c1; fr[4] = c2;
            fr[5] = op; fr[6] = rad;
            out_order[p] = (float)i;
        }
    }
}

extern "C" void kernel_launch(void* const* d_in, const int* in_sizes, int n_in,
                              void* d_out, int out_size, void* d_ws, size_t ws_size,
                              hipStream_t stream) {
    const float2* pos2d   = (const float2*)d_in[0];
    const float4* cov2d   = (const float4*)d_in[1];
    const float*  opacity = (const float*)d_in[2];
    const int N = in_sizes[2];           // opacity element count

    float* out         = (float*)d_out;  // layout: feat | counts | offsets | order
    float* out_feat    = out;
    float* out_counts  = out + (size_t)N * 7;
    float* out_offsets = out_counts + NTILES;
    float* out_order   = out_offsets + NTILES;

    int* gcounts = (int*)d_ws;
    int* gHist   = gcounts + NTILES;

    // Pick wave-chunk so the hist matrix fits ws and K2's 16-rows/thread bound.
    int wchunk = 512;
    for (;;) {
        int nw  = (N + wchunk - 1) / wchunk;
        int nb  = (nw + 3) / 4;
        int nwa = nb * 4;
        size_t need = ((size_t)nwa * NTILES + NTILES) * sizeof(int);
        if ((need <= ws_size && nwa <= 4096) || wchunk >= (1 << 22)) break;
        wchunk <<= 1;
    }
    int nw  = (N + wchunk - 1) / wchunk;
    int nb  = (nw + 3) / 4;
    int nwa = nb * 4;

    hipMemsetAsync(gcounts, 0, NTILES * sizeof(int), stream);
    k_hist<<<nb, 256, 0, stream>>>(pos2d, gHist, gcounts, N, wchunk);
    k_scan<<<NTILES, 256, 0, stream>>>(gcounts, gHist, out_counts, out_offsets, nwa);
    k_scatter<<<nb, 256, 0, stream>>>(pos2d, cov2d, opacity, gHist,
                                      out_feat, out_order, N, wchunk);
}

// Round 2
// 186.559 us; speedup vs baseline: 1.2276x; 1.2276x over previous
//
#include <hip/hip_runtime.h>

#define NT 16
#define NTILES 256
#define INV_TILE (1.0f/64.0f)
#define CHUNK 4096          // points per block
#define WPT (CHUNK/4)       // 1024 points per wave
#define ROUNDS (WPT/64)     // 16

__device__ __forceinline__ int tile_of(float x, float y) {
    int tx = (int)floorf(x * INV_TILE);
    tx = tx < 0 ? 0 : (tx > NT - 1 ? NT - 1 : tx);
    int ty = (int)floorf(y * INV_TILE);
    ty = ty < 0 ? 0 : (ty > NT - 1 ? NT - 1 : ty);
    return ty * NT + tx;
}

// 64-lane same-tile group mask via 8 ballots (tile id is 8 bits).
__device__ __forceinline__ unsigned long long match_mask(int t, bool valid) {
    unsigned long long m = ~0ull;
#pragma unroll
    for (int b = 0; b < 8; ++b) {
        unsigned long long bal = __ballot((t >> b) & 1);
        m &= ((t >> b) & 1) ? bal : ~bal;
    }
    m &= __ballot(valid);
    return m;
}

// K1: per-chunk (per-block) 256-bin histogram + global tile totals.
__global__ __launch_bounds__(256) void k_hist(const float2* __restrict__ pos2d,
                                              int* __restrict__ gHist,
                                              int* __restrict__ gcounts,
                                              int N) {
    __shared__ int counters[4][NTILES];
    const int tid = threadIdx.x;
    const int wl = tid >> 6, lane = tid & 63;
#pragma unroll
    for (int k = 0; k < 4; ++k) counters[wl][lane + 64 * k] = 0;  // wave-private
    const int wstart = blockIdx.x * CHUNK + wl * WPT;
    for (int r = 0; r < ROUNDS; ++r) {
        int i = wstart + r * 64 + lane;
        bool valid = i < N;
        int t = 0;
        if (valid) { float2 p = pos2d[i]; t = tile_of(p.x, p.y); }
        unsigned long long m = match_mask(t, valid);
        if (valid) {
            unsigned long long below = m & ((1ull << lane) - 1ull);
            if (below == 0ull) counters[wl][t] += __popcll(m);
        }
    }
    __syncthreads();
    int s = counters[0][tid] + counters[1][tid] + counters[2][tid] + counters[3][tid];
    gHist[(size_t)blockIdx.x * NTILES + tid] = s;
    if (s) atomicAdd(&gcounts[tid], s);
}

// K2: one block per tile. Cross-tile exclusive offset + column scan of the
// per-chunk hist rows (converted in place into per-chunk output bases).
// Supports up to 1024 chunk rows (N <= 4.19M).
__global__ __launch_bounds__(256) void k_scan(const int* __restrict__ gcounts,
                                              int* __restrict__ gHist,
                                              float* __restrict__ out_counts,
                                              float* __restrict__ out_offsets,
                                              int NWA) {
    const int t = blockIdx.x;
    const int tid = threadIdx.x;
    const int wl = tid >> 6, lane = tid & 63;
    __shared__ int sdata[NTILES];
    __shared__ int wsum[4];

    int v = (tid < t) ? gcounts[tid] : 0;            // offset_t = sum_{u<t}
    sdata[tid] = v;
    __syncthreads();
#pragma unroll
    for (int s = 128; s > 0; s >>= 1) {
        if (tid < s) sdata[tid] += sdata[tid + s];
        __syncthreads();
    }
    int offset_t = sdata[0];
    if (tid == 0) {
        out_counts[t]  = (float)gcounts[t];
        out_offsets[t] = (float)offset_t;
    }

    int vals[4];
    const int base_row = tid * 4;
#pragma unroll
    for (int k = 0; k < 4; ++k) {
        int row = base_row + k;
        vals[k] = (row < NWA) ? gHist[(size_t)row * NTILES + t] : 0;
    }
    int tv = vals[0] + vals[1] + vals[2] + vals[3];
    int x = tv;
#pragma unroll
    for (int s = 1; s < 64; s <<= 1) {
        int y = __shfl_up(x, s);
        if (lane >= s) x += y;
    }
    if (lane == 63) wsum[wl] = x;
    __syncthreads();
    int wprefix = 0;
    for (int u = 0; u < wl; ++u) wprefix += wsum[u];
    int running = offset_t + wprefix + (x - tv);
#pragma unroll
    for (int k = 0; k < 4; ++k) {
        int row = base_row + k;
        if (row < NWA) gHist[(size_t)row * NTILES + t] = running;
        running += vals[k];
    }
}

// K3: block-staged stable scatter.
// pass1: tile ids -> LDS + per-wave hist; scan -> per-wave bases;
// pass2: ballot ranks -> LDS permutation (slot[local_pos] = in-chunk offset);
// write-out: walk slots in order, gather inputs (L2-hot), write coalesced
// per-tile segments.
__global__ __launch_bounds__(256) void k_scatter(const float2* __restrict__ pos2d,
                                                 const float4* __restrict__ cov2d,
                                                 const float*  __restrict__ opacity,
                                                 const int*    __restrict__ gBase,
                                                 float* __restrict__ out_feat,
                                                 float* __restrict__ out_order,
                                                 int N) {
    __shared__ unsigned char  tileid[CHUNK];
    __shared__ unsigned short slot[CHUNK];
    __shared__ int cnt[4][NTILES];
    __shared__ int tstart[NTILES];
    __shared__ int gbase[NTILES];
    __shared__ int wsum[4];

    const int tid = threadIdx.x;
    const int wl = tid >> 6, lane = tid & 63;
    const int base_i = blockIdx.x * CHUNK;

    gbase[tid] = gBase[(size_t)blockIdx.x * NTILES + tid];   // coalesced 1KB row
#pragma unroll
    for (int k = 0; k < 4; ++k) cnt[wl][lane + 64 * k] = 0;  // wave-private

    const int wstart = base_i + wl * WPT;
    // ---- pass 1: tile ids + per-wave histogram ----
    for (int r = 0; r < ROUNDS; ++r) {
        int i = wstart + r * 64 + lane;
        bool valid = i < N;
        int t = 0;
        if (valid) { float2 p = pos2d[i]; t = tile_of(p.x, p.y); }
        tileid[wl * WPT + r * 64 + lane] = (unsigned char)t;
        unsigned long long m = match_mask(t, valid);
        if (valid) {
            unsigned long long below = m & ((1ull << lane) - 1ull);
            if (below == 0ull) cnt[wl][t] += __popcll(m);
        }
    }
    __syncthreads();

    // ---- block scan: per-tile start + per-wave bases (thread tid = tile) ----
    int c0 = cnt[0][tid], c1 = cnt[1][tid], c2 = cnt[2][tid], c3 = cnt[3][tid];
    int tot = c0 + c1 + c2 + c3;
    int x = tot;
#pragma unroll
    for (int s = 1; s < 64; s <<= 1) {
        int y = __shfl_up(x, s);
        if (lane >= s) x += y;
    }
    if (lane == 63) wsum[wl] = x;
    __syncthreads();
    int wpre = 0;
    for (int u = 0; u < wl; ++u) wpre += wsum[u];
    int excl = wpre + x - tot;                 // block-exclusive start of tile tid
    tstart[tid] = excl;
    cnt[0][tid] = excl;
    cnt[1][tid] = excl + c0;
    cnt[2][tid] = excl + c0 + c1;
    cnt[3][tid] = excl + c0 + c1 + c2;
    __syncthreads();

    // ---- pass 2: stable ranks -> LDS permutation ----
    for (int r = 0; r < ROUNDS; ++r) {
        int o = wl * WPT + r * 64 + lane;
        int i = base_i + o;
        bool valid = i < N;
        int t = tileid[o];
        unsigned long long m = match_mask(t, valid);
        if (valid) {
            unsigned long long below = m & ((1ull << lane) - 1ull);
            int rank = __popcll(below);
            int b = cnt[wl][t];                          // lockstep read-before-write
            if (below == 0ull) cnt[wl][t] = b + __popcll(m);
            slot[b + rank] = (unsigned short)o;
        }
    }
    __syncthreads();

    // ---- write-out: coalesced per-tile segments ----
    int nvalid = N - base_i;
    if (nvalid > CHUNK) nvalid = CHUNK;
    for (int j = tid; j < nvalid; j += 256) {
        int o = slot[j];
        int t = tileid[o];
        int dest = gbase[t] + (j - tstart[t]);
        int i = base_i + o;
        float2 p = pos2d[i];
        float4 cv = cov2d[i];
        float op = opacity[i];
        float a = cv.x, b = cv.y, c = cv.z, d = cv.w;
        float trace = a + d;
        float det = a * d - b * c;
        float term1 = 0.5f * trace;
        float term2 = 0.5f * sqrtf(fmaxf(trace * trace - 4.0f * det, 0.0f));
        float rad = fmaxf(term1 - term2, term1 + term2);
        float inv = 1.0f / det;
        float* fr = out_feat + (size_t)dest * 7;
        fr[0] = p.x; fr[1] = p.y; fr[2] = d * inv; fr[3] = -b * inv;
        fr[4] = a * inv; fr[5] = op; fr[6] = rad;
        out_order[dest] = (float)i;
    }
}

extern "C" void kernel_launch(void* const* d_in, const int* in_sizes, int n_in,
                              void* d_out, int out_size, void* d_ws, size_t ws_size,
                              hipStream_t stream) {
    const float2* pos2d   = (const float2*)d_in[0];
    const float4* cov2d   = (const float4*)d_in[1];
    const float*  opacity = (const float*)d_in[2];
    const int N = in_sizes[2];           // opacity element count

    float* out         = (float*)d_out;  // layout: feat | counts | offsets | order
    float* out_feat    = out;
    float* out_counts  = out + (size_t)N * 7;
    float* out_offsets = out_counts + NTILES;
    float* out_order   = out_offsets + NTILES;

    int* gcounts = (int*)d_ws;
    int* gHist   = gcounts + NTILES;

    int nchunks = (N + CHUNK - 1) / CHUNK;   // 489 for N=2M (K2 supports <=1024)

    hipMemsetAsync(gcounts, 0, NTILES * sizeof(int), stream);
    k_hist<<<nchunks, 256, 0, stream>>>(pos2d, gHist, gcounts, N);
    k_scan<<<NTILES, 256, 0, stream>>>(gcounts, gHist, out_counts, out_offsets, nchunks);
    k_scatter<<<nchunks, 256, 0, stream>>>(pos2d, cov2d, opacity, gHist,
                                           out_feat, out_order, N);
}

// Round 3
// 170.704 us; speedup vs baseline: 1.3416x; 1.0929x over previous
//
#include <hip/hip_runtime.h>

#define NT 16
#define NTILES 256
#define INV_TILE (1.0f/64.0f)
#define CHUNK 2048          // points per block
#define WPT (CHUNK/4)       // 512 points per wave
#define ROUNDS (WPT/64)     // 8

__device__ __forceinline__ int tile_of(float x, float y) {
    int tx = (int)floorf(x * INV_TILE);
    tx = tx < 0 ? 0 : (tx > NT - 1 ? NT - 1 : tx);
    int ty = (int)floorf(y * INV_TILE);
    ty = ty < 0 ? 0 : (ty > NT - 1 ? NT - 1 : ty);
    return ty * NT + tx;
}

// 64-lane same-tile group mask via 8 ballots (tile id is 8 bits).
__device__ __forceinline__ unsigned long long match_mask(int t, bool valid) {
    unsigned long long m = ~0ull;
#pragma unroll
    for (int b = 0; b < 8; ++b) {
        unsigned long long bal = __ballot((t >> b) & 1);
        m &= ((t >> b) & 1) ? bal : ~bal;
    }
    m &= __ballot(valid);
    return m;
}

// K1: per-chunk (per-block) 256-bin histogram + global tile totals.
__global__ __launch_bounds__(256) void k_hist(const float2* __restrict__ pos2d,
                                              int* __restrict__ gHist,
                                              int* __restrict__ gcounts,
                                              int N) {
    __shared__ int counters[4][NTILES];
    const int tid = threadIdx.x;
    const int wl = tid >> 6, lane = tid & 63;
#pragma unroll
    for (int k = 0; k < 4; ++k) counters[wl][lane + 64 * k] = 0;  // wave-private
    const int wstart = blockIdx.x * CHUNK + wl * WPT;
    for (int r = 0; r < ROUNDS; ++r) {
        int i = wstart + r * 64 + lane;
        bool valid = i < N;
        int t = 0;
        if (valid) { float2 p = pos2d[i]; t = tile_of(p.x, p.y); }
        unsigned long long m = match_mask(t, valid);
        if (valid) {
            unsigned long long below = m & ((1ull << lane) - 1ull);
            if (below == 0ull) counters[wl][t] += __popcll(m);
        }
    }
    __syncthreads();
    int s = counters[0][tid] + counters[1][tid] + counters[2][tid] + counters[3][tid];
    gHist[(size_t)blockIdx.x * NTILES + tid] = s;
    if (s) atomicAdd(&gcounts[tid], s);
}

// K2: one block per tile. Cross-tile exclusive offset + column scan of the
// per-chunk hist rows (converted in place into per-chunk output bases).
// Supports up to 1024 chunk rows (N <= 2.097M at CHUNK=2048).
__global__ __launch_bounds__(256) void k_scan(const int* __restrict__ gcounts,
                                              int* __restrict__ gHist,
                                              float* __restrict__ out_counts,
                                              float* __restrict__ out_offsets,
                                              int NWA) {
    const int t = blockIdx.x;
    const int tid = threadIdx.x;
    const int wl = tid >> 6, lane = tid & 63;
    __shared__ int sdata[NTILES];
    __shared__ int wsum[4];

    int v = (tid < t) ? gcounts[tid] : 0;            // offset_t = sum_{u<t}
    sdata[tid] = v;
    __syncthreads();
#pragma unroll
    for (int s = 128; s > 0; s >>= 1) {
        if (tid < s) sdata[tid] += sdata[tid + s];
        __syncthreads();
    }
    int offset_t = sdata[0];
    if (tid == 0) {
        out_counts[t]  = (float)gcounts[t];
        out_offsets[t] = (float)offset_t;
    }

    int vals[4];
    const int base_row = tid * 4;
#pragma unroll
    for (int k = 0; k < 4; ++k) {
        int row = base_row + k;
        vals[k] = (row < NWA) ? gHist[(size_t)row * NTILES + t] : 0;
    }
    int tv = vals[0] + vals[1] + vals[2] + vals[3];
    int x = tv;
#pragma unroll
    for (int s = 1; s < 64; s <<= 1) {
        int y = __shfl_up(x, s);
        if (lane >= s) x += y;
    }
    if (lane == 63) wsum[wl] = x;
    __syncthreads();
    int wprefix = 0;
    for (int u = 0; u < wl; ++u) wprefix += wsum[u];
    int running = offset_t + wprefix + (x - tv);
#pragma unroll
    for (int k = 0; k < 4; ++k) {
        int row = base_row + k;
        if (row < NWA) gHist[(size_t)row * NTILES + t] = running;
        running += vals[k];
    }
}

// K3: block-staged stable scatter, all-coalesced global traffic.
// pass1: coalesced pos2d -> per-wave hist (no tileid stored).
// scan:  per-tile block-local starts + per-wave bases.
// pass2: coalesced re-read of pos2d (L1-hot) + cov2d + opacity; compute
//        conic/radius; ballot rank -> stash 5 floats + packed (o,t) at the
//        block-local sorted position in LDS. cov2d read exactly once.
// write: walk sorted positions; pos2d gather is L1-resident (16KB/block);
//        global writes are coalesced per-tile runs.
__global__ __launch_bounds__(256) void k_scatter(const float2* __restrict__ pos2d,
                                                 const float4* __restrict__ cov2d,
                                                 const float*  __restrict__ opacity,
                                                 const int*    __restrict__ gBase,
                                                 float* __restrict__ out_feat,
                                                 float* __restrict__ out_order,
                                                 int N) {
    __shared__ float featS[CHUNK * 5];        // c0,c1,c2,op,rad at sorted pos
    __shared__ unsigned int slotPk[CHUNK];    // (t<<16) | o  at sorted pos
    __shared__ int cnt[4][NTILES];
    __shared__ int tstart[NTILES];
    __shared__ int gbase[NTILES];
    __shared__ int wsum[4];

    const int tid = threadIdx.x;
    const int wl = tid >> 6, lane = tid & 63;
    const int base_i = blockIdx.x * CHUNK;

    gbase[tid] = gBase[(size_t)blockIdx.x * NTILES + tid];   // coalesced 1KB row
#pragma unroll
    for (int k = 0; k < 4; ++k) cnt[wl][lane + 64 * k] = 0;  // wave-private

    const int wstart = base_i + wl * WPT;
    // ---- pass 1: per-wave histogram ----
    for (int r = 0; r < ROUNDS; ++r) {
        int i = wstart + r * 64 + lane;
        bool valid = i < N;
        int t = 0;
        if (valid) { float2 p = pos2d[i]; t = tile_of(p.x, p.y); }
        unsigned long long m = match_mask(t, valid);
        if (valid) {
            unsigned long long below = m & ((1ull << lane) - 1ull);
            if (below == 0ull) cnt[wl][t] += __popcll(m);
        }
    }
    __syncthreads();

    // ---- block scan: per-tile start + per-wave bases (thread tid = tile) ----
    int c0_ = cnt[0][tid], c1_ = cnt[1][tid], c2_ = cnt[2][tid], c3_ = cnt[3][tid];
    int tot = c0_ + c1_ + c2_ + c3_;
    int x = tot;
#pragma unroll
    for (int s = 1; s < 64; s <<= 1) {
        int y = __shfl_up(x, s);
        if (lane >= s) x += y;
    }
    if (lane == 63) wsum[wl] = x;
    __syncthreads();
    int wpre = 0;
    for (int u = 0; u < wl; ++u) wpre += wsum[u];
    int excl = wpre + x - tot;                 // block-exclusive start of tile tid
    tstart[tid] = excl;
    cnt[0][tid] = excl;
    cnt[1][tid] = excl + c0_;
    cnt[2][tid] = excl + c0_ + c1_;
    cnt[3][tid] = excl + c0_ + c1_ + c2_;
    __syncthreads();

    // ---- pass 2: compute features, stable rank -> LDS at sorted position ----
    for (int r = 0; r < ROUNDS; ++r) {
        int o = wl * WPT + r * 64 + lane;
        int i = base_i + o;
        bool valid = i < N;
        int t = 0;
        float c0 = 0, c1 = 0, c2 = 0, op = 0, rad = 0;
        if (valid) {
            float2 p = pos2d[i];               // L1-hot (read in pass1)
            t = tile_of(p.x, p.y);
            float4 cv = cov2d[i];              // first & only read, coalesced
            float a = cv.x, b = cv.y, c = cv.z, d = cv.w;
            float trace = a + d;
            float det = a * d - b * c;
            float term1 = 0.5f * trace;
            float term2 = 0.5f * sqrtf(fmaxf(trace * trace - 4.0f * det, 0.0f));
            rad = fmaxf(term1 - term2, term1 + term2);
            float inv = 1.0f / det;
            c0 = d * inv; c1 = -b * inv; c2 = a * inv;
            op = opacity[i];
        }
        unsigned long long m = match_mask(t, valid);
        if (valid) {
            unsigned long long below = m & ((1ull << lane) - 1ull);
            int rank = __popcll(below);
            int b = cnt[wl][t];                          // lockstep read-before-write
            if (below == 0ull) cnt[wl][t] = b + __popcll(m);
            int ldest = b + rank;                        // block-local sorted pos
            float* fs = featS + ldest * 5;               // stride 5: conflict-free
            fs[0] = c0; fs[1] = c1; fs[2] = c2; fs[3] = op; fs[4] = rad;
            slotPk[ldest] = ((unsigned int)t << 16) | (unsigned int)o;
        }
    }
    __syncthreads();

    // ---- write-out: coalesced per-tile segments ----
    int nvalid = N - base_i;
    if (nvalid > CHUNK) nvalid = CHUNK;
    for (int j = tid; j < nvalid; j += 256) {
        unsigned int pk = slotPk[j];
        int t = pk >> 16;
        int o = pk & 0xFFFF;
        int gdest = gbase[t] + (j - tstart[t]);
        int i = base_i + o;
        float2 p = pos2d[i];                   // L1-resident gather (16KB/block)
        const float* fs = featS + j * 5;
        float* fr = out_feat + (size_t)gdest * 7;
        fr[0] = p.x; fr[1] = p.y; fr[2] = fs[0]; fr[3] = fs[1];
        fr[4] = fs[2]; fr[5] = fs[3]; fr[6] = fs[4];
        out_order[gdest] = (float)i;
    }
}

extern "C" void kernel_launch(void* const* d_in, const int* in_sizes, int n_in,
                              void* d_out, int out_size, void* d_ws, size_t ws_size,
                              hipStream_t stream) {
    const float2* pos2d   = (const float2*)d_in[0];
    const float4* cov2d   = (const float4*)d_in[1];
    const float*  opacity = (const float*)d_in[2];
    const int N = in_sizes[2];           // opacity element count

    float* out         = (float*)d_out;  // layout: feat | counts | offsets | order
    float* out_feat    = out;
    float* out_counts  = out + (size_t)N * 7;
    float* out_offsets = out_counts + NTILES;
    float* out_order   = out_offsets + NTILES;

    int* gcounts = (int*)d_ws;
    int* gHist   = gcounts + NTILES;

    int nchunks = (N + CHUNK - 1) / CHUNK;   // 977 for N=2M (K2 supports <=1024)

    hipMemsetAsync(gcounts, 0, NTILES * sizeof(int), stream);
    k_hist<<<nchunks, 256, 0, stream>>>(pos2d, gHist, gcounts, N);
    k_scan<<<NTILES, 256, 0, stream>>>(gcounts, gHist, out_counts, out_offsets, nchunks);
    k_scatter<<<nchunks, 256, 0, stream>>>(pos2d, cov2d, opacity, gHist,
                                           out_feat, out_order, N);
}